// Round 8
// baseline (122.591 us; speedup 1.0000x reference)
//
#include <hip/hip_runtime.h>
#include <hip/hip_fp16.h>
#include <cstdint>
#include <cstddef>

// z = soft_thresh(Toeplitz(v) @ x + W2 @ y, beta) -- complex, N=1024, M=256, B=1024
// Real embedding: C[1024][2048] = A'[1024][2560] @ B'[2560][2048] (layouts R0-R5).
// Output = Re(z) only: [1024,1024] f32 (R4 finding).
//
// R8 (R7 showed per-dispatch overhead eats kernel gains; gemm latency-bound):
//  - build_A + build_Bt merged into ONE kernel (2560 blocks) -> 3 dispatches
//  - split-K=4 (K=640 each): 2048 blocks = 8 blocks/CU = 32 waves/CU (100% occ)
//  - dbuf LDS, one barrier/iter (R7); partials g_P[4] (32 MB static)
//  - reduce_soft sums 4 partials + soft-threshold

#define K_DIM 2560
#define BETA_F 0.01f
#define EPS_F  1e-12f

typedef __attribute__((ext_vector_type(8))) _Float16 half8;
typedef __attribute__((ext_vector_type(4))) _Float16 half4;
typedef __attribute__((ext_vector_type(4))) float   floatx4;

__device__ alignas(16) _Float16 g_Ap[1024 * K_DIM];      // 5 MB
__device__ alignas(16) _Float16 g_Bt[2048 * K_DIM];      // 10 MB
__device__ alignas(16) float    g_P[4][1024 * 2048];     // 32 MB split partials

// ---------------- prep (merged): build A' and B' -----------------------------
__global__ __launch_bounds__(256) void build_all(
    const float* __restrict__ v_re, const float* __restrict__ v_im,
    const float* __restrict__ W2_re, const float* __restrict__ W2_im,
    const float* __restrict__ x_re, const float* __restrict__ x_im,
    const float* __restrict__ y_re, const float* __restrict__ y_im)
{
    const int bx = blockIdx.x;
    if (bx < 1280) {
        // ---- A' part: one thread per 8 halves (16B store) ----
        int t = bx * 256 + threadIdx.x;
        int i  = t / 320;
        int c  = t - i * 320;
        int kp = c * 8;                        // segment-aligned
        half8 h;
        if (kp < 1024) {
#pragma unroll
            for (int j = 0; j < 8; ++j) h[j] = (_Float16)v_re[1023 + i - kp - j];
        } else if (kp < 1280) {
            const float* s = W2_re + i * 256 + (kp - 1024);
#pragma unroll
            for (int j = 0; j < 8; ++j) h[j] = (_Float16)s[j];
        } else if (kp < 2304) {
            int k2 = kp - 1280;
#pragma unroll
            for (int j = 0; j < 8; ++j) h[j] = (_Float16)v_im[1023 + i - k2 - j];
        } else {
            const float* s = W2_im + i * 256 + (kp - 2304);
#pragma unroll
            for (int j = 0; j < 8; ++j) h[j] = (_Float16)s[j];
        }
        *reinterpret_cast<half8*>(g_Ap + (size_t)i * K_DIM + kp) = h;
        return;
    }
    // ---- B' part: transposing build (was build_Bt, grid (40,32)) ----
    __shared__ float lre[32][33];
    __shared__ float lim[32][33];
    int idx = bx - 1280;                       // 0..1279
    int bk  = idx % 40;                        // 0..39 (k-block / source select)
    int by  = idx / 40;                        // 0..31 (n-block)
    const float* sre = (bk < 32) ? x_re : y_re;
    const float* sim = (bk < 32) ? x_im : y_im;
    int kb   = (bk < 32) ? bk : (bk - 32);
    int koff = (bk < 32) ? 0 : 1024;
    int k0 = kb * 32;
    int n0 = by * 32;
    int tid = threadIdx.x;
    int tx = tid & 31, ty = tid >> 5;
#pragma unroll
    for (int s = 0; s < 4; ++s) {
        int kk = ty + 8 * s;
        lre[kk][tx] = sre[(size_t)(k0 + kk) * 1024 + n0 + tx];
        lim[kk][tx] = sim[(size_t)(k0 + kk) * 1024 + n0 + tx];
    }
    __syncthreads();
    int lane_n = tid >> 3;                     // 0..31
    int kq     = (tid & 7) * 4;                // 0,4,...,28
    half4 hre, him, hmim;
#pragma unroll
    for (int j = 0; j < 4; ++j) {
        float re = lre[kq + j][lane_n];
        float im = lim[kq + j][lane_n];
        hre[j]  = (_Float16)re;
        him[j]  = (_Float16)im;
        hmim[j] = (_Float16)(-im);
    }
    int n = n0 + lane_n;
    size_t kk2 = (size_t)koff + k0 + kq;
    _Float16* r0 = g_Bt + (size_t)(2 * n)     * K_DIM;
    _Float16* r1 = g_Bt + (size_t)(2 * n + 1) * K_DIM;
    *reinterpret_cast<half4*>(r0 + kk2)        = hre;   // Br block of re-col
    *reinterpret_cast<half4*>(r0 + kk2 + 1280) = hmim;  // -Bi block of re-col
    *reinterpret_cast<half4*>(r1 + kk2)        = him;   // Bi block of im-col
    *reinterpret_cast<half4*>(r1 + kk2 + 1280) = hre;   // Br block of im-col
}

// ---------------- split-K=4 GEMM (partials only) -----------------------------
// 64x64 tile, BK=64, 2048 blocks (8/CU, 32 waves/CU), 4 waves = 2x2 of 32x32.
// Double-buffered LDS, one barrier per iter, XOR swizzle (0 conflicts R5-R7).
__global__ __launch_bounds__(256, 8) void gemm_split(void)
{
    __shared__ __align__(16) _Float16 As[2 * 2 * 64 * 32];  // [buf][ksub][row][32h]
    __shared__ __align__(16) _Float16 Bs[2 * 2 * 64 * 32];

    const int tid  = threadIdx.x;
    const int lane = tid & 63;
    const int w    = tid >> 6;
    const int wm   = w >> 1;
    const int wn   = w & 1;

    const int bid   = blockIdx.x;        // 0..2047
    const int xcd   = bid & 7;           // round-robin dispatch -> XCD id
    const int t     = bid >> 3;          // 0..255
    const int split = t & 3;
    const int tile  = t >> 2;            // 0..63 within XCD's 8x8 super-tile
    const int mi0 = ((xcd & 1) * 8 + (tile & 7)) * 64;    // 0..960
    const int ni0 = ((xcd >> 1) * 8 + (tile >> 3)) * 64;  // 0..1984
    const int ks  = split * 640;
    float* __restrict__ P = g_P[split];

    floatx4 acc[2][2];
#pragma unroll
    for (int a = 0; a < 2; ++a)
#pragma unroll
        for (int b = 0; b < 2; ++b) acc[a][b] = (floatx4)0.0f;

    const int rS = tid >> 2;
    const int jS = tid & 3;
    const int s0 = ((rS & 15) >> 1) & 3;
    char* asW = (char*)As + rS * 64 + ((jS ^ s0) * 16);
    char* bsW = (char*)Bs + rS * 64 + ((jS ^ s0) * 16);
    const _Float16* gA = g_Ap + (size_t)(mi0 + rS) * K_DIM + ks + jS * 8;
    const _Float16* gB = g_Bt + (size_t)(ni0 + rS) * K_DIM + ks + jS * 8;

    const int rowA = lane & 15;
    const int q    = lane >> 4;
    const int coff = (q ^ ((rowA >> 1) & 3)) * 16;

    {   // preload iter 0 -> buf 0
        half8 pA0 = *reinterpret_cast<const half8*>(gA);
        half8 pA1 = *reinterpret_cast<const half8*>(gA + 32);
        half8 pB0 = *reinterpret_cast<const half8*>(gB);
        half8 pB1 = *reinterpret_cast<const half8*>(gB + 32);
        *reinterpret_cast<half8*>(asW)        = pA0;
        *reinterpret_cast<half8*>(asW + 4096) = pA1;
        *reinterpret_cast<half8*>(bsW)        = pB0;
        *reinterpret_cast<half8*>(bsW + 4096) = pB1;
    }
    __syncthreads();

    const int NIT = 640 / 64;            // 10
    for (int kt = 0; kt < NIT; ++kt) {
        const int cur = kt & 1;
        half8 pA0, pA1, pB0, pB1;
        if (kt < NIT - 1) {              // issue next slab's global loads now
            const _Float16* ga = gA + (kt + 1) * 64;
            const _Float16* gb = gB + (kt + 1) * 64;
            pA0 = *reinterpret_cast<const half8*>(ga);
            pA1 = *reinterpret_cast<const half8*>(ga + 32);
            pB0 = *reinterpret_cast<const half8*>(gb);
            pB1 = *reinterpret_cast<const half8*>(gb + 32);
        }
        const char* Ab = (const char*)As + cur * 8192;
        const char* Bb = (const char*)Bs + cur * 8192;
        half8 af[2][2], bf[2][2];
#pragma unroll
        for (int mi = 0; mi < 2; ++mi) {
            int r = wm * 32 + mi * 16 + rowA;
            af[mi][0] = *reinterpret_cast<const half8*>(Ab + r * 64 + coff);
            af[mi][1] = *reinterpret_cast<const half8*>(Ab + 4096 + r * 64 + coff);
        }
#pragma unroll
        for (int ni = 0; ni < 2; ++ni) {
            int r = wn * 32 + ni * 16 + rowA;
            bf[ni][0] = *reinterpret_cast<const half8*>(Bb + r * 64 + coff);
            bf[ni][1] = *reinterpret_cast<const half8*>(Bb + 4096 + r * 64 + coff);
        }
#pragma unroll
        for (int mi = 0; mi < 2; ++mi)
#pragma unroll
            for (int ni = 0; ni < 2; ++ni) {
                acc[mi][ni] = __builtin_amdgcn_mfma_f32_16x16x32_f16(
                    af[mi][0], bf[ni][0], acc[mi][ni], 0, 0, 0);
                acc[mi][ni] = __builtin_amdgcn_mfma_f32_16x16x32_f16(
                    af[mi][1], bf[ni][1], acc[mi][ni], 0, 0, 0);
            }
        if (kt < NIT - 1) {              // store prefetch into the other buffer
            char* aw = asW + (cur ^ 1) * 8192;
            char* bw = bsW + (cur ^ 1) * 8192;
            *reinterpret_cast<half8*>(aw)        = pA0;
            *reinterpret_cast<half8*>(aw + 4096) = pA1;
            *reinterpret_cast<half8*>(bw)        = pB0;
            *reinterpret_cast<half8*>(bw + 4096) = pB1;
        }
        __syncthreads();                 // single barrier per iter
    }

    // store f32 partial tile (C/D layout: col=lane&15, row=(lane>>4)*4+reg)
    const int colL  = lane & 15;
    const int rquad = (lane >> 4) * 4;
#pragma unroll
    for (int mi = 0; mi < 2; ++mi)
#pragma unroll
        for (int ni = 0; ni < 2; ++ni)
#pragma unroll
            for (int r = 0; r < 4; ++r) {
                int row = mi0 + wm * 32 + mi * 16 + rquad + r;
                int col = ni0 + wn * 32 + ni * 16 + colL;
                P[(size_t)row * 2048 + col] = acc[mi][ni][r];
            }
}

// ---------------- epilogue: reduce 4 splits + complex soft-threshold --------
__global__ __launch_bounds__(256) void reduce_soft(float* __restrict__ out,
                                                   int out_n)
{
    int t = blockIdx.x * 256 + threadIdx.x;          // 0..524287
    floatx4 v0 = reinterpret_cast<const floatx4*>(g_P[0])[t];
    floatx4 v1 = reinterpret_cast<const floatx4*>(g_P[1])[t];
    floatx4 v2 = reinterpret_cast<const floatx4*>(g_P[2])[t];
    floatx4 v3 = reinterpret_cast<const floatx4*>(g_P[3])[t];
    float re0 = (v0[0] + v1[0]) + (v2[0] + v3[0]);
    float im0 = (v0[1] + v1[1]) + (v2[1] + v3[1]);
    float re1 = (v0[2] + v1[2]) + (v2[2] + v3[2]);
    float im1 = (v0[3] + v1[3]) + (v2[3] + v3[3]);
    float m0 = sqrtf(re0 * re0 + im0 * im0);
    float m1 = sqrtf(re1 * re1 + im1 * im1);
    float s0 = fmaxf(m0 - BETA_F, 0.0f) / fmaxf(m0, EPS_F);
    float s1 = fmaxf(m1 - BETA_F, 0.0f) / fmaxf(m1, EPS_F);
    float2 r = make_float2(re0 * s0, re1 * s1);
    int idx = t * 2;                                  // flat Re-output index
    if (idx + 1 < out_n)
        *reinterpret_cast<float2*>(out + idx) = r;
}

// ---------------- launcher ---------------------------------------------------
extern "C" void kernel_launch(void* const* d_in, const int* in_sizes, int n_in,
                              void* d_out, int out_size, void* d_ws, size_t ws_size,
                              hipStream_t stream) {
    (void)d_ws; (void)ws_size; (void)in_sizes; (void)n_in;
    const float* v_re  = (const float*)d_in[0];
    const float* v_im  = (const float*)d_in[1];
    const float* W2_re = (const float*)d_in[2];
    const float* W2_im = (const float*)d_in[3];
    const float* x_re  = (const float*)d_in[4];
    const float* x_im  = (const float*)d_in[5];
    const float* y_re  = (const float*)d_in[6];
    const float* y_im  = (const float*)d_in[7];
    float* out = (float*)d_out;

    build_all<<<2560, 256, 0, stream>>>(v_re, v_im, W2_re, W2_im,
                                        x_re, x_im, y_re, y_im);
    gemm_split<<<2048, 256, 0, stream>>>();
    reduce_soft<<<2048, 256, 0, stream>>>(out, out_size);
}